// Round 8
// baseline (192.628 us; speedup 1.0000x reference)
//
#include <hip/hip_runtime.h>

#define N_NODES 50000
#define N_EDGES 640000
#define N_SUP   3
#define D       128
#define NTOT    150000                   // 3 * 50000 global rows
#define E_TOT   1920000
#define NC      293                      // 512-row coarse buckets (grow>>9)
#define CAPC    7680                     // per-bucket cap: mean 6553 + ~14 sigma
#define CTILE   2048
#define CTPS    313                      // ceil(640000/2048) tiles per support
#define SBLKS   (N_SUP * CTPS)           // 939 edge tiles
#define XCBLKS  3125                     // (50000*128/4)/512 x-convert blocks
#define WBLKS   96                       // 49152/512 W-pack blocks
#define LDSTR   132                      // LDS row stride in shorts (128+4 pad)

typedef __attribute__((ext_vector_type(2))) float f32x2;
typedef __attribute__((ext_vector_type(4))) float f32x4;
typedef __attribute__((ext_vector_type(8))) short s16x8;

__device__ __forceinline__ unsigned short f2bf(float f) {   // RNE
    unsigned int u = __float_as_uint(f);
    u += 0x7FFFu + ((u >> 16) & 1u);
    return (unsigned short)(u >> 16);
}

// ---------------------------------------------------------------------------
// Pass 1: coarse scatter (R5-proven, untouched). LDS-staged bucket-sorted
// runs, atomic global bucket bases, uint2 staged edges.
// ---------------------------------------------------------------------------
__global__ __launch_bounds__(512) void prep_scatter(
    const int* __restrict__ rows, const int* __restrict__ cols,
    const float* __restrict__ vals, int* __restrict__ coarse_wptr,
    uint2* __restrict__ sortedA)
{
    __shared__ int          h[512];              // bucket histogram
    __shared__ int          toff[512];           // tile-local bucket offsets
    __shared__ int          gbase[512];          // global bucket bases
    __shared__ int          wsum[8];
    __shared__ uint2        stage[CTILE];        // 16 KB bucket-sorted edges
    __shared__ unsigned int dst[CTILE];          // 8 KB absolute dests

    int tid  = threadIdx.x;
    const int lane = tid & 63;
    const int w    = tid >> 6;

    h[tid] = 0;
    __syncthreads();

    int s  = blockIdx.x / CTPS;
    int tb = (blockIdx.x % CTPS) * CTILE;
    int n  = N_EDGES - tb; if (n > CTILE) n = CTILE;
    const int*   rp = rows + (size_t)s * N_EDGES + tb;
    const int*   cp = cols + (size_t)s * N_EDGES + tb;
    const float* vp = vals + (size_t)s * N_EDGES + tb;

    int bk[4], rk[4]; uint2 ed[4];
    #pragma unroll
    for (int i = 0; i < 4; ++i) {
        int idx = tid + i * 512;
        bk[i] = -1;
        if (idx < n) {
            int grow = s * N_NODES + rp[idx];
            bk[i] = grow >> 9;
            rk[i] = atomicAdd(&h[bk[i]], 1);     // within-tile bucket rank (LDS)
            ed[i] = make_uint2(((unsigned int)(grow & 511) << 16)
                               | (unsigned int)cp[idx],
                               (unsigned int)f2bf(vp[idx]) << 16);
        }
    }
    __syncthreads();
    int cntb = h[tid];

    int v = cntb;                                // wave inclusive scan
    #pragma unroll
    for (int d = 1; d < 64; d <<= 1) {
        int t = __shfl_up(v, d);
        v += (lane >= d) ? t : 0;
    }
    if (lane == 63) wsum[w] = v;
    __syncthreads();
    int add = 0;
    #pragma unroll
    for (int i = 0; i < 8; ++i) add += (i < w) ? wsum[i] : 0;
    int incl = v + add;

    toff[tid]  = incl - cntb;                    // tile-local exclusive
    gbase[tid] = (cntb > 0) ? atomicAdd(&coarse_wptr[tid * 16], cntb) : 0;
    __syncthreads();

    #pragma unroll
    for (int i = 0; i < 4; ++i) {
        if (bk[i] >= 0) {
            int slot  = toff[bk[i]] + rk[i];
            int gslot = gbase[bk[i]] + rk[i];
            stage[slot] = ed[i];
            dst[slot] = (gslot < CAPC)
                      ? (unsigned int)(bk[i] * CAPC + gslot)
                      : 0xFFFFFFFFu;             // never at +14 sigma
        }
    }
    __syncthreads();
    for (int j = tid; j < n; j += 512) {         // coalesced run writes
        unsigned int d = dst[j];
        if (d != 0xFFFFFFFFu) sortedA[d] = stage[j];
    }
}

// ---------------------------------------------------------------------------
// Pass 2: fine sort co-launched with converts (R5-proven, untouched).
// ---------------------------------------------------------------------------
__global__ __launch_bounds__(512) void sort_convert(
    const int* __restrict__ coarse_wptr, const uint2* __restrict__ sortedA,
    int* __restrict__ row_ptr2, unsigned int* __restrict__ sortedB,
    const float4* __restrict__ x, ushort4* __restrict__ xb,
    const float* __restrict__ W, unsigned short* __restrict__ Wf)
{
    int tid = threadIdx.x;

    if (blockIdx.x >= NC) {                      // -------- convert path ----
        int gid = (blockIdx.x - NC) * 512 + tid;
        if (gid < N_NODES * D / 4) {             // x -> bf16
            float4 v = x[gid];
            ushort4 o;
            o.x = f2bf(v.x); o.y = f2bf(v.y); o.z = f2bf(v.z); o.w = f2bf(v.w);
            xb[gid] = o;
        } else {                                 // W -> MFMA B-fragment order
            int g2 = gid - N_NODES * D / 4;
            if (g2 < N_SUP * D * D) {
                int j    = g2 & 7;
                int lane = (g2 >> 3) & 63;
                int rest = g2 >> 9;
                int nt = rest & 7, kb = (rest >> 3) & 3, s = rest >> 5;
                int k = kb * 32 + ((lane >> 4) * 8) + j;
                int n = nt * 16 + (lane & 15);
                Wf[g2] = f2bf(W[((size_t)s * D + k) * D + n]);
            }
        }
        return;
    }

    // ------------------------------- sort path ----------------------------
    int c   = blockIdx.x;
    int cnt = coarse_wptr[c * 16];
    if (cnt > CAPC) cnt = CAPC;

    __shared__ int hist[512];
    __shared__ int rank[512];
    __shared__ int wsum[8];
    int lane = tid & 63;
    int w    = tid >> 6;
    hist[tid] = 0;

    const uint2* src = sortedA + (size_t)c * CAPC;
    uint2 e[15];
    #pragma unroll
    for (int k = 0; k < 15; ++k) {               // independent loads
        int idx = tid + k * 512;
        if (idx < cnt) e[k] = src[idx];
    }
    __syncthreads();
    #pragma unroll
    for (int k = 0; k < 15; ++k) {
        int idx = tid + k * 512;
        if (idx < cnt) atomicAdd(&hist[e[k].x >> 16], 1);
    }
    __syncthreads();

    int cntb = hist[tid];
    int v = cntb;                                // wave inclusive scan
    #pragma unroll
    for (int d = 1; d < 64; d <<= 1) {
        int t = __shfl_up(v, d);
        v += (lane >= d) ? t : 0;
    }
    if (lane == 63) wsum[w] = v;
    __syncthreads();
    int add = 0;
    #pragma unroll
    for (int i = 0; i < 8; ++i) add += (i < w) ? wsum[i] : 0;
    int incl = v + add;

    int start = c * CAPC + incl - cntb;          // exclusive, bucket-based
    rank[tid] = start;
    row_ptr2[c * 513 + tid] = start;
    if (tid == 511) row_ptr2[c * 513 + 512] = c * CAPC + incl;
    __syncthreads();

    #pragma unroll
    for (int k = 0; k < 15; ++k) {
        int idx = tid + k * 512;
        if (idx < cnt) {
            int r = atomicAdd(&rank[e[k].x >> 16], 1);
            sortedB[r] = (e[k].y & 0xFFFF0000u) | (e[k].x & 0xFFFFu);
        }
    }
}

// ---------------------------------------------------------------------------
// FUSED gather + MFMA GEMM. Phase 1: the 3 support-rows of each 16-lane
// group are now INTERLEAVED in one merged chunk loop. R7's per-row ping-pong
// drained at every row boundary (rows are only ~12.8 edges = ~3 quartets, so
// the pipeline never reached steady state and drained 3x per group). Here
// each quartet-step issues loads for all 3 rows (12 dwordx4 in flight),
// consumes in order, and ev words prefetch a chunk ahead -- one drain per
// group. H2 discriminator: if dur stays ~62us with FETCH ~177MB, the
// beyond-L2 path is saturated -> algorithmic roofline. Phase 2 untouched.
// ---------------------------------------------------------------------------
#define LOADQ(EARR, XARR, EV, TQ)                                              \
    _Pragma("unroll")                                                          \
    for (int t = 0; t < 4; ++t) {                                              \
        EARR[t] = (unsigned int)__shfl((int)(EV), (int)(gsel + (TQ) * 4 + t)); \
        XARR[t] = *((const uint4*)(xb + (size_t)(EARR[t] & 0xFFFFu) * D) + gl);\
    }

#define FMAQ(EARR, XARR, A0, A1, A2, A3)                                       \
    _Pragma("unroll")                                                          \
    for (int t = 0; t < 4; ++t) {                                              \
        float v = __uint_as_float(EARR[t] & 0xFFFF0000u);                      \
        f32x2 vv = {v, v};                                                     \
        f32x2 x0 = {__uint_as_float(XARR[t].x << 16),                          \
                    __uint_as_float(XARR[t].x & 0xFFFF0000u)};                 \
        f32x2 x1 = {__uint_as_float(XARR[t].y << 16),                          \
                    __uint_as_float(XARR[t].y & 0xFFFF0000u)};                 \
        f32x2 x2 = {__uint_as_float(XARR[t].z << 16),                          \
                    __uint_as_float(XARR[t].z & 0xFFFF0000u)};                 \
        f32x2 x3 = {__uint_as_float(XARR[t].w << 16),                          \
                    __uint_as_float(XARR[t].w & 0xFFFF0000u)};                 \
        A0 += vv * x0; A1 += vv * x1; A2 += vv * x2; A3 += vv * x3;            \
    }

#define STOREROW(R, A0, A1, A2, A3)                                            \
    {                                                                          \
        uint2 o0, o1;                                                          \
        o0.x = (unsigned int)f2bf(A0.x) | ((unsigned int)f2bf(A0.y) << 16);    \
        o0.y = (unsigned int)f2bf(A1.x) | ((unsigned int)f2bf(A1.y) << 16);    \
        o1.x = (unsigned int)f2bf(A2.x) | ((unsigned int)f2bf(A2.y) << 16);    \
        o1.y = (unsigned int)f2bf(A3.x) | ((unsigned int)f2bf(A3.y) << 16);    \
        *(uint2*)(ys + (R) * LDSTR + gl * 8)     = o0;                         \
        *(uint2*)(ys + (R) * LDSTR + gl * 8 + 4) = o1;                         \
    }

__global__ __launch_bounds__(256, 4) void gather_gemm(
    const unsigned short* __restrict__ xb, const int* __restrict__ row_ptr2,
    const unsigned int* __restrict__ sortedB,
    const unsigned short* __restrict__ Wf,
    const float* __restrict__ bias, float* __restrict__ out)
{
    __shared__ unsigned short ys[48 * LDSTR];    // 12.7 KB
    __shared__ int rs[48], re[48];
    const int tid  = threadIdx.x;
    const int w    = tid >> 6;
    const int lane = tid & 63;
    const int m0   = blockIdx.x * 16;

    if (tid < 48) {
        int grow = (tid >> 4) * N_NODES + m0 + (tid & 15);
        int rpi  = (grow >> 9) * 513 + (grow & 511);
        rs[tid] = row_ptr2[rpi];
        re[tid] = row_ptr2[rpi + 1];
    }
    __syncthreads();

    // ---- phase 1: group-per-node gather, 3 supports interleaved ----
    const int gl = lane & 15;                    // lane in group: dims gl*8..+7
    const int G  = w * 4 + (lane >> 4);          // group id = node index 0..15
    const unsigned int gsel = (unsigned int)(lane & 48);  // group base lane

    int st0 = rs[G],      len0 = re[G]      - st0;
    int st1 = rs[16 + G], len1 = re[16 + G] - st1;
    int st2 = rs[32 + G], len2 = re[32 + G] - st2;
    int maxlen = len0 > len1 ? len0 : len1;
    maxlen = maxlen > len2 ? maxlen : len2;

    f32x2 p00 = {0.f,0.f}, p01 = {0.f,0.f}, p02 = {0.f,0.f}, p03 = {0.f,0.f};
    f32x2 p10 = {0.f,0.f}, p11 = {0.f,0.f}, p12 = {0.f,0.f}, p13 = {0.f,0.f};
    f32x2 p20 = {0.f,0.f}, p21 = {0.f,0.f}, p22 = {0.f,0.f}, p23 = {0.f,0.f};

    unsigned int ev0 = (gl < len0) ? sortedB[st0 + gl] : 0u;
    unsigned int ev1 = (gl < len1) ? sortedB[st1 + gl] : 0u;
    unsigned int ev2 = (gl < len2) ? sortedB[st2 + gl] : 0u;

    for (int base = 0; base < maxlen; base += 16) {   // 16-edge chunks
        int nb = base + 16;
        unsigned int evn0 = (nb + gl < len0) ? sortedB[st0 + nb + gl] : 0u;
        unsigned int evn1 = (nb + gl < len1) ? sortedB[st1 + nb + gl] : 0u;
        unsigned int evn2 = (nb + gl < len2) ? sortedB[st2 + nb + gl] : 0u;

        #pragma unroll
        for (int q = 0; q < 4; ++q) {
            int eb = base + q * 4;
            bool a0 = eb < len0, a1 = eb < len1, a2 = eb < len2;
            unsigned int e0[4], e1[4], e2[4];
            uint4 X0[4], X1[4], X2[4];
            if (a0) LOADQ(e0, X0, ev0, q);       // 12 loads in flight
            if (a1) LOADQ(e1, X1, ev1, q);
            if (a2) LOADQ(e2, X2, ev2, q);
            if (a0) FMAQ(e0, X0, p00, p01, p02, p03);
            if (a1) FMAQ(e1, X1, p10, p11, p12, p13);
            if (a2) FMAQ(e2, X2, p20, p21, p22, p23);
        }
        ev0 = evn0; ev1 = evn1; ev2 = evn2;
    }

    STOREROW(G,      p00, p01, p02, p03);
    STOREROW(16 + G, p10, p11, p12, p13);
    STOREROW(32 + G, p20, p21, p22, p23);
    __syncthreads();

    // ---- phase 2: MFMA GEMM, wave w -> nt {2w, 2w+1} (untouched) ----
    const int quad = lane >> 4;
    const int l16  = lane & 15;
    const int nt0  = w * 2;
    f32x4 acc0 = {0.f, 0.f, 0.f, 0.f}, acc1 = {0.f, 0.f, 0.f, 0.f};

    #pragma unroll
    for (int s = 0; s < N_SUP; ++s) {
        #pragma unroll
        for (int kb = 0; kb < 4; ++kb) {
            union { uint2 q[2]; s16x8 v; } A;
            const unsigned short* ap = ys + (s * 16 + l16) * LDSTR
                                          + kb * 32 + quad * 8;
            A.q[0] = *(const uint2*)ap;          // 8B-aligned LDS reads
            A.q[1] = *(const uint2*)(ap + 4);
            const unsigned short* wf = Wf + (size_t)((s * 4 + kb) * 8 + nt0) * 64 * 8
                                          + lane * 8;
            s16x8 b0 = *(const s16x8*)wf;
            s16x8 b1 = *(const s16x8*)(wf + 64 * 8);
            acc0 = __builtin_amdgcn_mfma_f32_16x16x32_bf16(A.v, b0, acc0, 0, 0, 0);
            acc1 = __builtin_amdgcn_mfma_f32_16x16x32_bf16(A.v, b1, acc1, 0, 0, 0);
        }
    }

    #pragma unroll
    for (int p = 0; p < 2; ++p) {
        int col = (nt0 + p) * 16 + l16;
        float bv = bias[col];
        f32x4 a = p ? acc1 : acc0;
        #pragma unroll
        for (int r = 0; r < 4; ++r) {
            int row = m0 + quad * 4 + r;
            out[(size_t)row * D + col] = fmaxf(a[r] + bv, 0.f);
        }
    }
}

extern "C" void kernel_launch(void* const* d_in, const int* in_sizes, int n_in,
                              void* d_out, int out_size, void* d_ws, size_t ws_size,
                              hipStream_t stream)
{
    const float* x         = (const float*)d_in[0];
    const int*   edge_rows = (const int*)  d_in[1];
    const int*   edge_cols = (const int*)  d_in[2];
    const float* edge_vals = (const float*)d_in[3];
    const float* weights   = (const float*)d_in[4];
    const float* bias      = (const float*)d_in[5];
    float* out = (float*)d_out;

    // workspace layout (256B aligned), ~40 MB total
    char* ws = (char*)d_ws;
    size_t off = 0;
    auto alloc = [&](size_t bytes) -> char* {
        char* p = ws + off;
        off += (bytes + 255) & ~(size_t)255;
        return p;
    };
    int*            coarse_wptr = (int*)            alloc(512 * 16 * 4);
    int*            row_ptr2    = (int*)            alloc((size_t)NC * 513 * 4);
    unsigned short* xb          = (unsigned short*) alloc((size_t)N_NODES * D * 2);
    unsigned short* Wf          = (unsigned short*) alloc((size_t)N_SUP * D * D * 2);
    uint2*          sortedA     = (uint2*)          alloc((size_t)NC * CAPC * 8);
    unsigned int*   sortedB     = (unsigned int*)   alloc((size_t)NC * CAPC * 4);

    hipMemsetAsync(coarse_wptr, 0, 512 * 16 * 4, stream);
    prep_scatter<<<SBLKS, 512, 0, stream>>>(
        edge_rows, edge_cols, edge_vals, coarse_wptr, sortedA);
    sort_convert<<<NC + XCBLKS + WBLKS, 512, 0, stream>>>(
        coarse_wptr, sortedA, row_ptr2, sortedB,
        (const float4*)x, (ushort4*)xb, weights, Wf);
    gather_gemm<<<N_NODES / 16, 256, 0, stream>>>(xb, row_ptr2, sortedB,
                                                  Wf, bias, out);
}

// Round 9
// 184.007 us; speedup vs baseline: 1.0469x; 1.0469x over previous
//
#include <hip/hip_runtime.h>

#define N_NODES 50000
#define N_EDGES 640000
#define N_SUP   3
#define D       128
#define NTOT    150000                   // 3 * 50000 global rows
#define E_TOT   1920000
#define NC      293                      // 512-row coarse buckets (grow>>9)
#define CAPC    7680                     // per-bucket cap: mean 6553 + ~14 sigma
#define CTILE   2048
#define CTPS    313                      // ceil(640000/2048) tiles per support
#define SBLKS   (N_SUP * CTPS)           // 939 edge tiles
#define XCBLKS  3125                     // (50000*128/4)/512 x-convert blocks
#define WBLKS   96                       // 49152/512 W-pack blocks
#define LDSTR   132                      // LDS row stride in shorts (128+4 pad)

typedef __attribute__((ext_vector_type(2))) float f32x2;
typedef __attribute__((ext_vector_type(4))) float f32x4;
typedef __attribute__((ext_vector_type(8))) short s16x8;

__device__ __forceinline__ unsigned short f2bf(float f) {   // RNE
    unsigned int u = __float_as_uint(f);
    u += 0x7FFFu + ((u >> 16) & 1u);
    return (unsigned short)(u >> 16);
}

// ---------------------------------------------------------------------------
// Pass 1: coarse scatter (R5-proven, untouched). LDS-staged bucket-sorted
// runs, atomic global bucket bases, uint2 staged edges.
// ---------------------------------------------------------------------------
__global__ __launch_bounds__(512) void prep_scatter(
    const int* __restrict__ rows, const int* __restrict__ cols,
    const float* __restrict__ vals, int* __restrict__ coarse_wptr,
    uint2* __restrict__ sortedA)
{
    __shared__ int          h[512];              // bucket histogram
    __shared__ int          toff[512];           // tile-local bucket offsets
    __shared__ int          gbase[512];          // global bucket bases
    __shared__ int          wsum[8];
    __shared__ uint2        stage[CTILE];        // 16 KB bucket-sorted edges
    __shared__ unsigned int dst[CTILE];          // 8 KB absolute dests

    int tid  = threadIdx.x;
    const int lane = tid & 63;
    const int w    = tid >> 6;

    h[tid] = 0;
    __syncthreads();

    int s  = blockIdx.x / CTPS;
    int tb = (blockIdx.x % CTPS) * CTILE;
    int n  = N_EDGES - tb; if (n > CTILE) n = CTILE;
    const int*   rp = rows + (size_t)s * N_EDGES + tb;
    const int*   cp = cols + (size_t)s * N_EDGES + tb;
    const float* vp = vals + (size_t)s * N_EDGES + tb;

    int bk[4], rk[4]; uint2 ed[4];
    #pragma unroll
    for (int i = 0; i < 4; ++i) {
        int idx = tid + i * 512;
        bk[i] = -1;
        if (idx < n) {
            int grow = s * N_NODES + rp[idx];
            bk[i] = grow >> 9;
            rk[i] = atomicAdd(&h[bk[i]], 1);     // within-tile bucket rank (LDS)
            ed[i] = make_uint2(((unsigned int)(grow & 511) << 16)
                               | (unsigned int)cp[idx],
                               (unsigned int)f2bf(vp[idx]) << 16);
        }
    }
    __syncthreads();
    int cntb = h[tid];

    int v = cntb;                                // wave inclusive scan
    #pragma unroll
    for (int d = 1; d < 64; d <<= 1) {
        int t = __shfl_up(v, d);
        v += (lane >= d) ? t : 0;
    }
    if (lane == 63) wsum[w] = v;
    __syncthreads();
    int add = 0;
    #pragma unroll
    for (int i = 0; i < 8; ++i) add += (i < w) ? wsum[i] : 0;
    int incl = v + add;

    toff[tid]  = incl - cntb;                    // tile-local exclusive
    gbase[tid] = (cntb > 0) ? atomicAdd(&coarse_wptr[tid * 16], cntb) : 0;
    __syncthreads();

    #pragma unroll
    for (int i = 0; i < 4; ++i) {
        if (bk[i] >= 0) {
            int slot  = toff[bk[i]] + rk[i];
            int gslot = gbase[bk[i]] + rk[i];
            stage[slot] = ed[i];
            dst[slot] = (gslot < CAPC)
                      ? (unsigned int)(bk[i] * CAPC + gslot)
                      : 0xFFFFFFFFu;             // never at +14 sigma
        }
    }
    __syncthreads();
    for (int j = tid; j < n; j += 512) {         // coalesced run writes
        unsigned int d = dst[j];
        if (d != 0xFFFFFFFFu) sortedA[d] = stage[j];
    }
}

// ---------------------------------------------------------------------------
// Pass 2: fine sort co-launched with converts (R5-proven, untouched).
// ---------------------------------------------------------------------------
__global__ __launch_bounds__(512) void sort_convert(
    const int* __restrict__ coarse_wptr, const uint2* __restrict__ sortedA,
    int* __restrict__ row_ptr2, unsigned int* __restrict__ sortedB,
    const float4* __restrict__ x, ushort4* __restrict__ xb,
    const float* __restrict__ W, unsigned short* __restrict__ Wf)
{
    int tid = threadIdx.x;

    if (blockIdx.x >= NC) {                      // -------- convert path ----
        int gid = (blockIdx.x - NC) * 512 + tid;
        if (gid < N_NODES * D / 4) {             // x -> bf16
            float4 v = x[gid];
            ushort4 o;
            o.x = f2bf(v.x); o.y = f2bf(v.y); o.z = f2bf(v.z); o.w = f2bf(v.w);
            xb[gid] = o;
        } else {                                 // W -> MFMA B-fragment order
            int g2 = gid - N_NODES * D / 4;
            if (g2 < N_SUP * D * D) {
                int j    = g2 & 7;
                int lane = (g2 >> 3) & 63;
                int rest = g2 >> 9;
                int nt = rest & 7, kb = (rest >> 3) & 3, s = rest >> 5;
                int k = kb * 32 + ((lane >> 4) * 8) + j;
                int n = nt * 16 + (lane & 15);
                Wf[g2] = f2bf(W[((size_t)s * D + k) * D + n]);
            }
        }
        return;
    }

    // ------------------------------- sort path ----------------------------
    int c   = blockIdx.x;
    int cnt = coarse_wptr[c * 16];
    if (cnt > CAPC) cnt = CAPC;

    __shared__ int hist[512];
    __shared__ int rank[512];
    __shared__ int wsum[8];
    int lane = tid & 63;
    int w    = tid >> 6;
    hist[tid] = 0;

    const uint2* src = sortedA + (size_t)c * CAPC;
    uint2 e[15];
    #pragma unroll
    for (int k = 0; k < 15; ++k) {               // independent loads
        int idx = tid + k * 512;
        if (idx < cnt) e[k] = src[idx];
    }
    __syncthreads();
    #pragma unroll
    for (int k = 0; k < 15; ++k) {
        int idx = tid + k * 512;
        if (idx < cnt) atomicAdd(&hist[e[k].x >> 16], 1);
    }
    __syncthreads();

    int cntb = hist[tid];
    int v = cntb;                                // wave inclusive scan
    #pragma unroll
    for (int d = 1; d < 64; d <<= 1) {
        int t = __shfl_up(v, d);
        v += (lane >= d) ? t : 0;
    }
    if (lane == 63) wsum[w] = v;
    __syncthreads();
    int add = 0;
    #pragma unroll
    for (int i = 0; i < 8; ++i) add += (i < w) ? wsum[i] : 0;
    int incl = v + add;

    int start = c * CAPC + incl - cntb;          // exclusive, bucket-based
    rank[tid] = start;
    row_ptr2[c * 513 + tid] = start;
    if (tid == 511) row_ptr2[c * 513 + 512] = c * CAPC + incl;
    __syncthreads();

    #pragma unroll
    for (int k = 0; k < 15; ++k) {
        int idx = tid + k * 512;
        if (idx < cnt) {
            int r = atomicAdd(&rank[e[k].x >> 16], 1);
            sortedB[r] = (e[k].y & 0xFFFF0000u) | (e[k].x & 0xFFFFu);
        }
    }
}

// ---------------------------------------------------------------------------
// FUSED gather + MFMA GEMM (R7 exact revert -- session best, 62.9us).
// Phase 1: 4 groups of 16 lanes per wave; group G owns node m0+G's rows
// {G, G+16, G+32}. Per edge the group reads the full 256-B x-row as ONE
// dwordx4/lane; two quartets ping-pong (8 loads in flight); next chunk's
// sortedB word prefetched. MLP bracket established R6/R7/R8 (4/8/12-deep:
// 66.4/62.9/80.8us): 8-deep is the sweet spot; deeper costs VGPR/occupancy.
// Beyond-L2 delivery ~2.9 TB/s on random 256-B granules = path saturation.
// ---------------------------------------------------------------------------
#define LOADQ(EARR, XARR, TQ)                                                  \
    _Pragma("unroll")                                                          \
    for (int t = 0; t < 4; ++t) {                                              \
        EARR[t] = (unsigned int)__shfl((int)ev, (int)(gsel + (TQ) * 4 + t));   \
        XARR[t] = *((const uint4*)(xb + (size_t)(EARR[t] & 0xFFFFu) * D) + gl);\
    }

#define FMAQ(EARR, XARR)                                                       \
    _Pragma("unroll")                                                          \
    for (int t = 0; t < 4; ++t) {                                              \
        float v = __uint_as_float(EARR[t] & 0xFFFF0000u);                      \
        f32x2 vv = {v, v};                                                     \
        f32x2 x0 = {__uint_as_float(XARR[t].x << 16),                          \
                    __uint_as_float(XARR[t].x & 0xFFFF0000u)};                 \
        f32x2 x1 = {__uint_as_float(XARR[t].y << 16),                          \
                    __uint_as_float(XARR[t].y & 0xFFFF0000u)};                 \
        f32x2 x2 = {__uint_as_float(XARR[t].z << 16),                          \
                    __uint_as_float(XARR[t].z & 0xFFFF0000u)};                 \
        f32x2 x3 = {__uint_as_float(XARR[t].w << 16),                          \
                    __uint_as_float(XARR[t].w & 0xFFFF0000u)};                 \
        a0 += vv * x0; a1 += vv * x1; a2 += vv * x2; a3 += vv * x3;            \
    }

__global__ __launch_bounds__(256, 4) void gather_gemm(
    const unsigned short* __restrict__ xb, const int* __restrict__ row_ptr2,
    const unsigned int* __restrict__ sortedB,
    const unsigned short* __restrict__ Wf,
    const float* __restrict__ bias, float* __restrict__ out)
{
    __shared__ unsigned short ys[48 * LDSTR];    // 12.7 KB
    __shared__ int rs[48], re[48];
    const int tid  = threadIdx.x;
    const int w    = tid >> 6;
    const int lane = tid & 63;
    const int m0   = blockIdx.x * 16;

    if (tid < 48) {
        int grow = (tid >> 4) * N_NODES + m0 + (tid & 15);
        int rpi  = (grow >> 9) * 513 + (grow & 511);
        rs[tid] = row_ptr2[rpi];
        re[tid] = row_ptr2[rpi + 1];
    }
    __syncthreads();

    // ---- phase 1: group-per-row gather, ping-pong pipelined ----
    const int gl = lane & 15;                    // lane in group: dims gl*8..+7
    const int G  = w * 4 + (lane >> 4);          // group id = node index 0..15
    const unsigned int gsel = (unsigned int)(lane & 48);  // group base lane

    #pragma unroll
    for (int sp = 0; sp < N_SUP; ++sp) {
        int r = sp * 16 + G;
        int start = rs[r], end = re[r];
        f32x2 a0 = {0.f, 0.f}, a1 = {0.f, 0.f};
        f32x2 a2 = {0.f, 0.f}, a3 = {0.f, 0.f};

        unsigned int ev = (start + gl < end) ? sortedB[start + gl] : 0u;
        for (int j = start; j < end; j += 16) {  // 16-edge chunks
            unsigned int evn = (j + 16 + gl < end) ? sortedB[j + 16 + gl] : 0u;
            bool q1 = (j + 4 < end), q2 = (j + 8 < end), q3 = (j + 12 < end);
            unsigned int eA[4], eB[4];
            uint4 XA[4], XB[4];
            LOADQ(eA, XA, 0);                    // 4 loads in flight
            if (q1) LOADQ(eB, XB, 1);            // 8 in flight
            FMAQ(eA, XA);                        // consume Q0
            if (q2) LOADQ(eA, XA, 2);            // refill
            if (q1) FMAQ(eB, XB);                // consume Q1
            if (q3) LOADQ(eB, XB, 3);            // refill
            if (q2) FMAQ(eA, XA);                // consume Q2
            if (q3) FMAQ(eB, XB);                // consume Q3
            ev = evn;
        }
        uint2 o0, o1;
        o0.x = (unsigned int)f2bf(a0.x) | ((unsigned int)f2bf(a0.y) << 16);
        o0.y = (unsigned int)f2bf(a1.x) | ((unsigned int)f2bf(a1.y) << 16);
        o1.x = (unsigned int)f2bf(a2.x) | ((unsigned int)f2bf(a2.y) << 16);
        o1.y = (unsigned int)f2bf(a3.x) | ((unsigned int)f2bf(a3.y) << 16);
        *(uint2*)(ys + r * LDSTR + gl * 8)     = o0;   // 8B-aligned
        *(uint2*)(ys + r * LDSTR + gl * 8 + 4) = o1;
    }
    __syncthreads();

    // ---- phase 2: MFMA GEMM, wave w -> nt {2w, 2w+1} (untouched) ----
    const int quad = lane >> 4;
    const int l16  = lane & 15;
    const int nt0  = w * 2;
    f32x4 acc0 = {0.f, 0.f, 0.f, 0.f}, acc1 = {0.f, 0.f, 0.f, 0.f};

    #pragma unroll
    for (int s = 0; s < N_SUP; ++s) {
        #pragma unroll
        for (int kb = 0; kb < 4; ++kb) {
            union { uint2 q[2]; s16x8 v; } A;
            const unsigned short* ap = ys + (s * 16 + l16) * LDSTR
                                          + kb * 32 + quad * 8;
            A.q[0] = *(const uint2*)ap;          // 8B-aligned LDS reads
            A.q[1] = *(const uint2*)(ap + 4);
            const unsigned short* wf = Wf + (size_t)((s * 4 + kb) * 8 + nt0) * 64 * 8
                                          + lane * 8;
            s16x8 b0 = *(const s16x8*)wf;
            s16x8 b1 = *(const s16x8*)(wf + 64 * 8);
            acc0 = __builtin_amdgcn_mfma_f32_16x16x32_bf16(A.v, b0, acc0, 0, 0, 0);
            acc1 = __builtin_amdgcn_mfma_f32_16x16x32_bf16(A.v, b1, acc1, 0, 0, 0);
        }
    }

    #pragma unroll
    for (int p = 0; p < 2; ++p) {
        int col = (nt0 + p) * 16 + l16;
        float bv = bias[col];
        f32x4 a = p ? acc1 : acc0;
        #pragma unroll
        for (int r = 0; r < 4; ++r) {
            int row = m0 + quad * 4 + r;
            out[(size_t)row * D + col] = fmaxf(a[r] + bv, 0.f);
        }
    }
}

extern "C" void kernel_launch(void* const* d_in, const int* in_sizes, int n_in,
                              void* d_out, int out_size, void* d_ws, size_t ws_size,
                              hipStream_t stream)
{
    const float* x         = (const float*)d_in[0];
    const int*   edge_rows = (const int*)  d_in[1];
    const int*   edge_cols = (const int*)  d_in[2];
    const float* edge_vals = (const float*)d_in[3];
    const float* weights   = (const float*)d_in[4];
    const float* bias      = (const float*)d_in[5];
    float* out = (float*)d_out;

    // workspace layout (256B aligned), ~40 MB total
    char* ws = (char*)d_ws;
    size_t off = 0;
    auto alloc = [&](size_t bytes) -> char* {
        char* p = ws + off;
        off += (bytes + 255) & ~(size_t)255;
        return p;
    };
    int*            coarse_wptr = (int*)            alloc(512 * 16 * 4);
    int*            row_ptr2    = (int*)            alloc((size_t)NC * 513 * 4);
    unsigned short* xb          = (unsigned short*) alloc((size_t)N_NODES * D * 2);
    unsigned short* Wf          = (unsigned short*) alloc((size_t)N_SUP * D * D * 2);
    uint2*          sortedA     = (uint2*)          alloc((size_t)NC * CAPC * 8);
    unsigned int*   sortedB     = (unsigned int*)   alloc((size_t)NC * CAPC * 4);

    hipMemsetAsync(coarse_wptr, 0, 512 * 16 * 4, stream);
    prep_scatter<<<SBLKS, 512, 0, stream>>>(
        edge_rows, edge_cols, edge_vals, coarse_wptr, sortedA);
    sort_convert<<<NC + XCBLKS + WBLKS, 512, 0, stream>>>(
        coarse_wptr, sortedA, row_ptr2, sortedB,
        (const float4*)x, (ushort4*)xb, weights, Wf);
    gather_gemm<<<N_NODES / 16, 256, 0, stream>>>(xb, row_ptr2, sortedB,
                                                  Wf, bias, out);
}